// Round 10
// baseline (202.687 us; speedup 1.0000x reference)
//
#include <hip/hip_runtime.h>

#define B_   64
#define NQ_  1024
#define L_   128
#define E_   8192
#define M_   (B_*NQ_)
#define LDP  136        // padded LDS row stride (shorts)
#define TILE 2176       // 16*LDP u16 per tile

typedef unsigned short u16;
typedef unsigned int   u32;
typedef __attribute__((ext_vector_type(8))) short short8;
typedef __attribute__((ext_vector_type(4))) float floatx4;

#define WVB() __builtin_amdgcn_wave_barrier()

__device__ __forceinline__ u16 f2bf(float f) {
    union { float f; u32 u; } v; v.f = f;
    return (u16)((v.u + 0x7fffu + ((v.u >> 16) & 1u)) >> 16);
}
__device__ __forceinline__ float bf2f(u16 u) {
    union { u32 u; float f; } v; v.u = ((u32)u) << 16;
    return v.f;
}
__device__ __forceinline__ floatx4 mfma16(short8 a, short8 b, floatx4 c) {
    return __builtin_amdgcn_mfma_f32_16x16x32_bf16(a, b, c, 0, 0, 0);
}
__device__ __forceinline__ short8 gfrag(const u16* base, int r0, int kb, int lane) {
    return *(const short8*)(base + (size_t)(r0 + (lane & 15)) * 128 + kb * 32 + (lane >> 4) * 8);
}
__device__ __forceinline__ short8 sfrag(const u16* t, int r0, int kb, int lane) {
    return *(const short8*)(t + (r0 + (lane & 15)) * LDP + kb * 32 + (lane >> 4) * 8);
}
// fragment-major weight fetch: coalesced 16B/lane from global (L2-hot)
__device__ __forceinline__ short8 wfrag(const u16* wf, int nt, int kb, int lane) {
    return *(const short8*)(wf + (((kb << 3) + nt) * 64 + lane) * 8);
}
__device__ __forceinline__ void frag_flush(const u16* t, u16* wf, int nt, int lane) {
#pragma unroll
    for (int kb = 0; kb < 4; ++kb)
        *(short8*)(wf + (((kb << 3) + nt) * 64 + lane) * 8) = sfrag(t, 0, kb, lane);
}
__device__ __forceinline__ short8 frag_cvt(const float* base, int r0, int ld, int kb, int lane) {
    const float* p = base + (size_t)(r0 + (lane & 15)) * ld + kb * 32 + (lane >> 4) * 8;
    short8 s;
#pragma unroll
    for (int j = 0; j < 8; ++j) s[j] = (short)f2bf(p[j]);
    return s;
}
__device__ __forceinline__ void tile_store(u16* t, const floatx4* acc, int lane) {
    int col = lane & 15, qd = lane >> 4;
#pragma unroll
    for (int nt = 0; nt < 8; ++nt)
#pragma unroll
        for (int r = 0; r < 4; ++r)
            t[(qd * 4 + r) * LDP + nt * 16 + col] = f2bf(acc[nt][r]);
}
__device__ __forceinline__ void tile_flush(const u16* t, u16* g, int lane) {
#pragma unroll
    for (int it = 0; it < 4; ++it) {
        int chunk = it * 64 + lane, row = chunk >> 4, c8 = chunk & 15;
        *(uint4*)(g + (size_t)row * 128 + c8 * 8) = *(const uint4*)(t + row * LDP + c8 * 8);
    }
}

struct P {
    const int* ei; const float* attr; const float* z0;
    const float* e_w1; const float* e_b1; const float* e_w2; const float* e_b2;
    const float* n_w1; const float* n_b1; const float* ln_g; const float* ln_b;
    const float* n_w2; const float* n_b2;
    int* ofs; int* tgt_s; float* a_s; float* degf;
    u16* wf;        // 6 fragment-major slots: 0=Wc0 1=Wd 2=We 3=Wf 4=Wc1 5=n2_1
    u16* w_n20;     // n2_0 row-major (fin GEMV)
    float* wl; float* vb2;
    float* rx; float* rci; float* rcj; float* rh; float* mx0;
    u16* c0t; u16* S; u16* t1g; u16* ci1; u16* cj1;
    float* out;
};

// ---------------------------------------------------------------------------
// Setup, 20 blocks (latency-parallelized):
// 0 CSR; 1-2 n2_0 cvt; 3 n2_1->frag; 4-13 product GEMMs (2 blocks each,
// direct global B loads, no LDS staging); 14 rx; 15-17 rci/rcj/rh; 18 c0;
// 19 vb2(vectorized)+wl+zero mx0
// ---------------------------------------------------------------------------
__global__ __launch_bounds__(256) void k_setup(P p) {
    __shared__ __align__(16) char smem[17408];
    int tid = threadIdx.x, blk = blockIdx.x;
    int lane = tid & 63, w = tid >> 6, col = lane & 15, qd = lane >> 4;

    if (blk == 0) {                               // CSR build
        __shared__ int cnt[1024];
        __shared__ int wsum[4];
        __shared__ int flag;
#pragma unroll
        for (int i = 0; i < 4; ++i) cnt[tid + i * 256] = 0;
        if (tid == 0) flag = 1;
        __syncthreads();
        if (tid < 100 && p.ei[2 * tid + 1] != 0) atomicAnd(&flag, 0);
        __syncthreads();
        int i64 = flag;
        for (int e = tid; e < E_; e += 256) {
            int s = i64 ? p.ei[2 * e] : p.ei[e];
            atomicAdd(&cnt[s], 1);
        }
        __syncthreads();
        int q0 = tid * 4;
        int c0 = cnt[q0], c1 = cnt[q0 + 1], c2 = cnt[q0 + 2], c3 = cnt[q0 + 3];
        int tsum = c0 + c1 + c2 + c3, incl = tsum;
#pragma unroll
        for (int o = 1; o < 64; o <<= 1) {
            int t = __shfl_up(incl, o, 64);
            if (lane >= o) incl += t;
        }
        if (lane == 63) wsum[w] = incl;
        __syncthreads();
        int wo = 0;
        for (int i = 0; i < w; ++i) wo += wsum[i];
        int base = wo + incl - tsum;
        p.ofs[q0] = base; p.ofs[q0 + 1] = base + c0;
        p.ofs[q0 + 2] = base + c0 + c1; p.ofs[q0 + 3] = base + c0 + c1 + c2;
        p.degf[q0] = (float)c0; p.degf[q0 + 1] = (float)c1;
        p.degf[q0 + 2] = (float)c2; p.degf[q0 + 3] = (float)c3;
        if (tid == 0) p.ofs[NQ_] = E_;
        __syncthreads();
        cnt[q0] = base; cnt[q0 + 1] = base + c0;
        cnt[q0 + 2] = base + c0 + c1; cnt[q0 + 3] = base + c0 + c1 + c2;
        __syncthreads();
        for (int e = tid; e < E_; e += 256) {
            int s = i64 ? p.ei[2 * e]        : p.ei[e];
            int t = i64 ? p.ei[2 * (E_ + e)] : p.ei[E_ + e];
            int pos = atomicAdd(&cnt[s], 1);
            p.tgt_s[pos] = t;
            p.a_s[pos]   = p.attr[e];
        }
    } else if (blk <= 2) {                        // n2_0 row-major cvt, 2 halves
        int base = (blk - 1) * 8192;
        for (int idx = tid; idx < 8192; idx += 256)
            p.w_n20[base + idx] = f2bf(p.n_w2[base + idx]);
    } else if (blk == 3) {                        // n2_1 -> fragment-major slot 5
        const float* src = p.n_w2 + 16384;
        u16* dst = p.wf + 5 * 16384;
        for (int pr = w; pr < 32; pr += 4) {      // pr = kb*8+nt
            int kb = pr >> 3, nt = pr & 7;
            const float* s = src + (nt * 16 + col) * 128 + kb * 32 + qd * 8;
            short8 v;
#pragma unroll
            for (int j = 0; j < 8; ++j) v[j] = (short)f2bf(s[j]);
            *(short8*)(dst + (pr * 64 + lane) * 8) = v;
        }
    } else if (blk <= 13) {                       // product GEMMs, direct B loads
        int g = (blk - 4) >> 1, part = (blk - 4) & 1;
        const float* Pm; const float* Q; int ldp; u16* D;
        switch (g) {
            case 0:  Pm = p.n_w1 + 128;             ldp = 256; Q = p.e_w2;         D = p.wf;             break;
            case 1:  Pm = p.n_w1 + 32768 + 128;     ldp = 256; Q = p.e_w2 + 16384; D = p.wf + 4 * 16384; break;
            case 2:  Pm = p.e_w1 + 128 * 257;       ldp = 257; Q = p.n_w2;         D = p.wf + 1 * 16384; break;
            case 3:  Pm = p.e_w1 + 128 * 257 + 128; ldp = 257; Q = p.n_w2;         D = p.wf + 2 * 16384; break;
            default: Pm = p.n_w1 + 32768;           ldp = 256; Q = p.n_w2;         D = p.wf + 3 * 16384; break;
        }
        int tile = part * 4 + w;                  // 0..7, one 16-row tile per wave
        int r0 = tile * 16;
        floatx4 acc[8] = {};
#pragma unroll
        for (int kb = 0; kb < 4; ++kb) {
            short8 a = frag_cvt(Pm, r0, ldp, kb, lane);
#pragma unroll
            for (int nt = 0; nt < 8; ++nt) {
                short8 bq;                        // B[k][n] = Q[k*128+n], coalesced
#pragma unroll
                for (int j = 0; j < 8; ++j)
                    bq[j] = (short)f2bf(Q[(kb * 32 + qd * 8 + j) * 128 + nt * 16 + col]);
                acc[nt] = mfma16(a, bq, acc[nt]);
            }
        }
        u16* slot = (u16*)smem + w * TILE;
        tile_store(slot, acc, lane); WVB();
        frag_flush(slot, D, tile, lane);
    } else if (blk == 14) {                       // rx = z0@n1a0^T + n_b1_0
        int r0 = w * 16;
        floatx4 acc[8] = {};
#pragma unroll
        for (int kb = 0; kb < 4; ++kb) {
            short8 a = frag_cvt(p.z0, r0, 128, kb, lane);
#pragma unroll
            for (int nt = 0; nt < 8; ++nt)
                acc[nt] = mfma16(a, frag_cvt(p.n_w1, nt * 16, 256, kb, lane), acc[nt]);
        }
#pragma unroll
        for (int nt = 0; nt < 8; ++nt) {
            int cg = nt * 16 + col; float bv = p.n_b1[cg];
#pragma unroll
            for (int r = 0; r < 4; ++r) p.rx[(r0 + qd * 4 + r) * 128 + cg] = acc[nt][r] + bv;
        }
    } else if (blk <= 17) {                       // rci/rcj/rh = (z0+n_b2_0)@W^T (+bias)
        int r0 = w * 16;
        const float* Wp; int ld; const float* bias; float* dst;
        if (blk == 15)      { Wp = p.e_w1 + 128 * 257;       ld = 257; bias = p.e_b1 + 128; dst = p.rci; }
        else if (blk == 16) { Wp = p.e_w1 + 128 * 257 + 128; ld = 257; bias = nullptr;      dst = p.rcj; }
        else                { Wp = p.n_w1 + 32768;           ld = 256; bias = p.n_b1 + 128; dst = p.rh;  }
        floatx4 acc[8] = {};
#pragma unroll
        for (int kb = 0; kb < 4; ++kb) {
            short8 a;
            int rr = (r0 + col) * 128, kk = kb * 32 + qd * 8;
#pragma unroll
            for (int j = 0; j < 8; ++j) a[j] = (short)f2bf(p.z0[rr + kk + j] + p.n_b2[kk + j]);
#pragma unroll
            for (int nt = 0; nt < 8; ++nt)
                acc[nt] = mfma16(a, frag_cvt(Wp, nt * 16, ld, kb, lane), acc[nt]);
        }
#pragma unroll
        for (int nt = 0; nt < 8; ++nt) {
            int cg = nt * 16 + col;
            float bv = bias ? bias[cg] : 0.0f;
#pragma unroll
            for (int r = 0; r < 4; ++r) dst[(r0 + qd * 4 + r) * 128 + cg] = acc[nt][r] + bv;
        }
    } else if (blk == 18) {                       // c0 = z0@(W1a0+W1b0)^T + e_b1_0
        int r0 = w * 16;
        floatx4 a1[8] = {};
#pragma unroll
        for (int kb = 0; kb < 4; ++kb) {
            short8 a = frag_cvt(p.z0, r0, 128, kb, lane);
#pragma unroll
            for (int nt = 0; nt < 8; ++nt) {
                a1[nt] = mfma16(a, frag_cvt(p.e_w1,       nt * 16, 257, kb, lane), a1[nt]);
                a1[nt] = mfma16(a, frag_cvt(p.e_w1 + 128, nt * 16, 257, kb, lane), a1[nt]);
            }
        }
#pragma unroll
        for (int nt = 0; nt < 8; ++nt) {
            float bv = p.e_b1[nt * 16 + col];
#pragma unroll
            for (int r = 0; r < 4; ++r) a1[nt][r] += bv;
        }
        u16* slot = (u16*)smem + w * TILE;
        tile_store(slot, a1, lane); WVB();
        tile_flush(slot, p.c0t + (size_t)r0 * 128, lane);
    } else {                                      // vb2 (vectorized) + wl + zero mx0
        int k = tid >> 7, c = tid & 127;
        const float4* wp = (const float4*)(p.n_w1 + k * 32768 + c * 256 + 128);
        const float4* bp = (const float4*)(p.e_b2 + k * 128);
        float s0 = 0.f, s1 = 0.f, s2 = 0.f, s3 = 0.f;
#pragma unroll
        for (int n4 = 0; n4 < 32; ++n4) {
            float4 a = wp[n4], bv = bp[n4];
            s0 += a.x * bv.x; s1 += a.y * bv.y; s2 += a.z * bv.z; s3 += a.w * bv.w;
        }
        p.vb2[tid] = (s0 + s1) + (s2 + s3);
        p.wl[tid]  = p.e_w1[k * 128 * 257 + c * 257 + 256];
        for (int i = tid; i < 8192; i += 256) p.mx0[i] = 0.0f;
    }
}

// ---------------------------------------------------------------------------
// Edge gather round 1: wave = one q x 8 batches (shared index stream)
// ---------------------------------------------------------------------------
__global__ __launch_bounds__(256) void k_edge(P p) {
    int tid = threadIdx.x, lane = tid & 63, w = tid >> 6;
    const float* wl = p.wl + 128;
    float2 wl2 = ((const float2*)wl)[lane];
    int gw = blockIdx.x * 4 + w;
    int q = gw & (NQ_ - 1), bg = gw >> 10;
    int bl[8];
#pragma unroll
    for (int i = 0; i < 4; ++i) { bl[i] = bg * 4 + i; bl[i + 4] = bg * 4 + i + 32; }
    int st = p.ofs[q], en = p.ofs[q + 1];
    float ax[8] = {}, ay[8] = {};
    const u32* cjp[8];
    float cx[8], cy[8];
#pragma unroll
    for (int i = 0; i < 8; ++i) {
        cjp[i] = (const u32*)p.cj1 + (size_t)bl[i] * NQ_ * 64;
        u32 cv = ((const u32*)p.ci1)[((size_t)bl[i] * NQ_ + q) * 64 + lane];
        cx[i] = bf2f((u16)(cv & 0xffff)); cy[i] = bf2f((u16)(cv >> 16));
    }
    for (int idx = st; idx < en; ++idx) {
        int t = p.tgt_s[idx];
        float a = p.a_s[idx];
        size_t ro = (size_t)t * 64 + lane;
        float wx = a * wl2.x, wy = a * wl2.y;
#pragma unroll
        for (int i = 0; i < 8; ++i) {
            u32 jv = cjp[i][ro];
            ax[i] += fmaxf(cx[i] + bf2f((u16)(jv & 0xffff)) + wx, 0.f);
            ay[i] += fmaxf(cy[i] + bf2f((u16)(jv >> 16))    + wy, 0.f);
        }
    }
    u32* Sp = (u32*)p.S;
#pragma unroll
    for (int i = 0; i < 8; ++i)
        Sp[((size_t)bl[i] * NQ_ + q) * 64 + lane] =
            (u32)f2bf(ax[i]) | ((u32)f2bf(ay[i]) << 16);
}

// ---------------------------------------------------------------------------
// node0: wave-uniform fused round-0 gather -> wave-private LDS S0 tiles;
//   x0 = LN(relu(S0@Wc0 + rx + deg*vb2)); wave-direct mx0 atomics;
//   ci1 = x0@Wd + rci; cj1 = x0@We + rcj; t1 = x0@Wf + rh -> t1g
// ---------------------------------------------------------------------------
__global__ __launch_bounds__(256, 2) void k_node0(P p) {
    __shared__ __align__(16) char smem[52224];
    u16* xt = (u16*)smem;
    u16* ob = (u16*)(smem + 34816);
    int tid = threadIdx.x, lane = tid & 63, w = tid >> 6;
    int col = lane & 15, qd = lane >> 4;
    int blk = blockIdx.x;
    int rowbase = blk * 128 + w * 32;
    int b = blk >> 3;

    // ---- fused round-0 gather: wave computes S0 for its own 32 q rows.
    // Per q (wave-uniform edge loop): lanes cover the 128 l's (2 per lane).
    {
        u32 cv = ((const u32*)p.c0t)[b * 64 + lane];
        float c0x = bf2f((u16)(cv & 0xffff)), c0y = bf2f((u16)(cv >> 16));
        float2 wl2 = ((const float2*)p.wl)[lane];
#pragma unroll
        for (int t = 0; t < 2; ++t) {
            u32* tslot = (u32*)(xt + (w * 2 + t) * TILE);
            for (int r16 = 0; r16 < 16; ++r16) {
                int q = (rowbase + t * 16 + r16) & (NQ_ - 1);
                int st = p.ofs[q], en = p.ofs[q + 1];
                float ax = 0.f, ay = 0.f;
                for (int idx = st; idx < en; ++idx) {
                    float a = p.a_s[idx];
                    ax += fmaxf(fmaf(a, wl2.x, c0x), 0.f);
                    ay += fmaxf(fmaf(a, wl2.y, c0y), 0.f);
                }
                tslot[r16 * 68 + lane] = (u32)f2bf(ax) | ((u32)f2bf(ay) << 16);
            }
        }
    }
    WVB();

    floatx4 xa[2][8] = {};
#pragma unroll
    for (int kb = 0; kb < 4; ++kb) {
        short8 Bv[8];
#pragma unroll
        for (int nt = 0; nt < 8; ++nt) Bv[nt] = wfrag(p.wf, nt, kb, lane);
#pragma unroll
        for (int t = 0; t < 2; ++t) {
            short8 a = sfrag(xt + (w * 2 + t) * TILE, 0, kb, lane);
#pragma unroll
            for (int nt = 0; nt < 8; ++nt) xa[t][nt] = mfma16(a, Bv[nt], xa[t][nt]);
        }
    }
    WVB();                                // S0 tiles consumed; slots reused for x0
    float s8[8] = {};
#pragma unroll
    for (int t = 0; t < 2; ++t) {
#pragma unroll
        for (int nt = 0; nt < 8; ++nt) {
            int cg = nt * 16 + col;
            float base = p.rx[b * 128 + cg], vb = p.vb2[cg];
#pragma unroll
            for (int r = 0; r < 4; ++r) {
                int row = rowbase + t * 16 + qd * 4 + r;
                xa[t][nt][r] = fmaxf(xa[t][nt][r] + base + p.degf[row & (NQ_ - 1)] * vb, 0.f);
            }
        }
#pragma unroll
        for (int r = 0; r < 4; ++r) {
            float s = 0.f, s2 = 0.f;
#pragma unroll
            for (int nt = 0; nt < 8; ++nt) { float v = xa[t][nt][r]; s += v; s2 += v * v; }
#pragma unroll
            for (int o = 1; o < 16; o <<= 1) { s += __shfl_xor(s, o, 64); s2 += __shfl_xor(s2, o, 64); }
            float mu = s * (1.f / 128.f), var = s2 * (1.f / 128.f) - mu * mu;
            float rs = rsqrtf(var + 1e-5f);
#pragma unroll
            for (int nt = 0; nt < 8; ++nt) {
                int cg = nt * 16 + col;
                float xv = (xa[t][nt][r] - mu) * rs * p.ln_g[cg] + p.ln_b[cg];
                xa[t][nt][r] = xv;
                s8[nt] += xv;
            }
        }
        tile_store(xt + (w * 2 + t) * TILE, xa[t], lane);
    }
#pragma unroll
    for (int nt = 0; nt < 8; ++nt) {
        s8[nt] += __shfl_xor(s8[nt], 16, 64);
        s8[nt] += __shfl_xor(s8[nt], 32, 64);
    }
    if (lane < 16) {
#pragma unroll
        for (int nt = 0; nt < 8; ++nt)
            atomicAdd(p.mx0 + b * 128 + nt * 16 + lane, s8[nt]);
    }
    WVB();
#pragma unroll
    for (int ph = 0; ph < 3; ++ph) {
        const u16* wfp = p.wf + ((ph == 0) ? 1 : (ph == 1) ? 2 : 3) * 16384;
        const float* rt = (ph == 0) ? p.rci : (ph == 1) ? p.rcj : p.rh;
        floatx4 ca[2][8] = {};
#pragma unroll
        for (int kb = 0; kb < 4; ++kb) {
            short8 Bv[8];
#pragma unroll
            for (int nt = 0; nt < 8; ++nt) Bv[nt] = wfrag(wfp, nt, kb, lane);
#pragma unroll
            for (int t = 0; t < 2; ++t) {
                short8 a = sfrag(xt + (w * 2 + t) * TILE, 0, kb, lane);
#pragma unroll
                for (int nt = 0; nt < 8; ++nt) ca[t][nt] = mfma16(a, Bv[nt], ca[t][nt]);
            }
        }
#pragma unroll
        for (int t = 0; t < 2; ++t)
#pragma unroll
            for (int nt = 0; nt < 8; ++nt) {
                float rc = rt[b * 128 + nt * 16 + col];
#pragma unroll
                for (int r = 0; r < 4; ++r) ca[t][nt][r] += rc;
            }
        u16* dst = (ph == 0) ? p.ci1 : (ph == 1) ? p.cj1 : p.t1g;
#pragma unroll
        for (int t = 0; t < 2; ++t) {
            tile_store(ob + w * TILE, ca[t], lane);
            WVB();
            tile_flush(ob + w * TILE, dst + (size_t)(rowbase + t * 16) * 128, lane);
            WVB();
        }
    }
}

// ---------------------------------------------------------------------------
// node1: x1 = LN(relu(S@Wc1 + t1 + deg*vb2_1)); out += mean(x1@n2_1); fin
// ---------------------------------------------------------------------------
__global__ __launch_bounds__(256, 2) void k_node1(P p) {
    __shared__ __align__(16) char smem[52224];
    u16* ob = (u16*)(smem + 34816);
    int tid = threadIdx.x, lane = tid & 63, w = tid >> 6;
    int col = lane & 15, qd = lane >> 4;
    int blk = blockIdx.x;
    int rowbase = blk * 128 + w * 32;
    int b = blk >> 3;

    const u16* wc1 = p.wf + 4 * 16384;
    floatx4 xa[2][8] = {};
#pragma unroll
    for (int kb = 0; kb < 4; ++kb) {
        short8 Bv[8];
#pragma unroll
        for (int nt = 0; nt < 8; ++nt) Bv[nt] = wfrag(wc1, nt, kb, lane);
#pragma unroll
        for (int t = 0; t < 2; ++t) {
            short8 a = gfrag(p.S, rowbase + t * 16, kb, lane);
#pragma unroll
            for (int nt = 0; nt < 8; ++nt) xa[t][nt] = mfma16(a, Bv[nt], xa[t][nt]);
        }
    }
    const float* vb21 = p.vb2 + 128;
#pragma unroll
    for (int t = 0; t < 2; ++t) {
#pragma unroll
        for (int nt = 0; nt < 8; ++nt) {
            int cg = nt * 16 + col;
            float vb = vb21[cg];
#pragma unroll
            for (int r = 0; r < 4; ++r) {
                int row = rowbase + t * 16 + qd * 4 + r;
                float tv = bf2f(p.t1g[(size_t)row * 128 + cg]);
                xa[t][nt][r] = fmaxf(xa[t][nt][r] + tv + p.degf[row & (NQ_ - 1)] * vb, 0.f);
            }
        }
#pragma unroll
        for (int r = 0; r < 4; ++r) {
            float s = 0.f, s2 = 0.f;
#pragma unroll
            for (int nt = 0; nt < 8; ++nt) { float v = xa[t][nt][r]; s += v; s2 += v * v; }
#pragma unroll
            for (int o = 1; o < 16; o <<= 1) { s += __shfl_xor(s, o, 64); s2 += __shfl_xor(s2, o, 64); }
            float mu = s * (1.f / 128.f), var = s2 * (1.f / 128.f) - mu * mu;
            float rs = rsqrtf(var + 1e-5f);
#pragma unroll
            for (int nt = 0; nt < 8; ++nt) {
                int cg = nt * 16 + col;
                xa[t][nt][r] = (xa[t][nt][r] - mu) * rs * p.ln_g[128 + cg] + p.ln_b[128 + cg];
            }
        }
    }
    // mean(x1@n2_1): per-wave sequential staging through ob slot
    const u16* n21 = p.wf + 5 * 16384;
    float s8[8] = {};
#pragma unroll
    for (int t = 0; t < 2; ++t) {
        WVB();
        tile_store(ob + w * TILE, xa[t], lane);
        WVB();
        floatx4 ma[8] = {};
#pragma unroll
        for (int kb = 0; kb < 4; ++kb) {
            short8 Bv[8];
#pragma unroll
            for (int nt = 0; nt < 8; ++nt) Bv[nt] = wfrag(n21, nt, kb, lane);
            short8 a = sfrag(ob + w * TILE, 0, kb, lane);
#pragma unroll
            for (int nt = 0; nt < 8; ++nt) ma[nt] = mfma16(a, Bv[nt], ma[nt]);
        }
#pragma unroll
        for (int nt = 0; nt < 8; ++nt)
#pragma unroll
            for (int r = 0; r < 4; ++r) s8[nt] += ma[nt][r];
    }
#pragma unroll
    for (int nt = 0; nt < 8; ++nt) {
        s8[nt] += __shfl_xor(s8[nt], 16, 64);
        s8[nt] += __shfl_xor(s8[nt], 32, 64);
    }
    if (lane < 16) {
#pragma unroll
        for (int nt = 0; nt < 8; ++nt)
            atomicAdd(p.out + b * 128 + nt * 16 + lane, s8[nt] * (1.f / 1024.f));
    }
    // fin: out[b] += z0[b] + n_b2_0 + n_b2_1 + mx0[b]@n2_0^T / 1024  (vectorized)
    if ((blk & 7) == 0 && tid < 128) {
        int c = tid;
        const float* mx = p.mx0 + b * 128;
        float s = 0.f;
#pragma unroll
        for (int k8 = 0; k8 < 16; ++k8) {
            short8 wv = *(const short8*)(p.w_n20 + c * 128 + k8 * 8);
            const float* mxp = mx + k8 * 8;
#pragma unroll
            for (int j = 0; j < 8; ++j) s += mxp[j] * bf2f((u16)wv[j]);
        }
        float acc = p.z0[b * 128 + c] + p.n_b2[c] + p.n_b2[128 + c] + s * (1.f / 1024.f);
        atomicAdd(p.out + b * 128 + c, acc);
    }
}

// ---------------------------------------------------------------------------
extern "C" void kernel_launch(void* const* d_in, const int* in_sizes, int n_in,
                              void* d_out, int out_size, void* d_ws, size_t ws_size,
                              hipStream_t stream) {
    P p;
    p.z0   = (const float*)d_in[0];
    p.ei   = (const int*)d_in[1];
    p.attr = (const float*)d_in[2];
    p.e_w1 = (const float*)d_in[4];
    p.e_b1 = (const float*)d_in[5];
    p.e_w2 = (const float*)d_in[6];
    p.e_b2 = (const float*)d_in[7];
    p.n_w1 = (const float*)d_in[8];
    p.n_b1 = (const float*)d_in[9];
    p.ln_g = (const float*)d_in[10];
    p.ln_b = (const float*)d_in[11];
    p.n_w2 = (const float*)d_in[12];
    p.n_b2 = (const float*)d_in[13];
    p.out  = (float*)d_out;

    const size_t H = (size_t)M_ * L_;
    float* f  = (float*)d_ws;
    p.degf = f;                           // 1024
    p.a_s  = f + 1024;                    // 8192
    p.wl   = p.a_s + 8192;                // 256
    p.vb2  = p.wl + 256;                  // 256
    p.rx   = p.vb2 + 256;                 // 8192
    p.rci  = p.rx + 8192;                 // 8192
    p.rcj  = p.rci + 8192;                // 8192
    p.rh   = p.rcj + 8192;                // 8192
    p.mx0  = p.rh + 8192;                 // 8192
    p.ofs  = (int*)(p.mx0 + 8192);        // 1056
    p.tgt_s = p.ofs + 1056;               // 8192
    p.wf    = (u16*)(p.tgt_s + 8192);     // 6*16384
    p.w_n20 = p.wf + 6 * 16384;           // 16384
    p.c0t   = p.w_n20 + 16384;            // 8192
    p.S     = p.c0t + 8192;               // H
    p.t1g   = p.S + H;                    // H
    p.ci1   = p.t1g + H;                  // H
    p.cj1   = p.ci1 + H;                  // H

    hipMemsetAsync(p.out, 0, 8192 * sizeof(float), stream);

    k_setup<<<20, 256, 0, stream>>>(p);
    k_node0<<<512, 256, 0, stream>>>(p);
    k_edge<<<2048, 256, 0, stream>>>(p);
    k_node1<<<512, 256, 0, stream>>>(p);
}

// Round 11
// 189.808 us; speedup vs baseline: 1.0679x; 1.0679x over previous
//
#include <hip/hip_runtime.h>

#define B_   64
#define NQ_  1024
#define L_   128
#define E_   8192
#define M_   (B_*NQ_)
#define LDP  136        // padded LDS row stride (shorts)
#define TILE 2176       // 16*LDP u16 per tile

typedef unsigned short u16;
typedef unsigned int   u32;
typedef __attribute__((ext_vector_type(8))) short short8;
typedef __attribute__((ext_vector_type(4))) float floatx4;

#define WVB() __builtin_amdgcn_wave_barrier()

__device__ __forceinline__ u16 f2bf(float f) {
    union { float f; u32 u; } v; v.f = f;
    return (u16)((v.u + 0x7fffu + ((v.u >> 16) & 1u)) >> 16);
}
__device__ __forceinline__ float bf2f(u16 u) {
    union { u32 u; float f; } v; v.u = ((u32)u) << 16;
    return v.f;
}
__device__ __forceinline__ floatx4 mfma16(short8 a, short8 b, floatx4 c) {
    return __builtin_amdgcn_mfma_f32_16x16x32_bf16(a, b, c, 0, 0, 0);
}
__device__ __forceinline__ short8 gfrag(const u16* base, int r0, int kb, int lane) {
    return *(const short8*)(base + (size_t)(r0 + (lane & 15)) * 128 + kb * 32 + (lane >> 4) * 8);
}
__device__ __forceinline__ short8 sfrag(const u16* t, int r0, int kb, int lane) {
    return *(const short8*)(t + (r0 + (lane & 15)) * LDP + kb * 32 + (lane >> 4) * 8);
}
// fragment-major weight fetch: coalesced 16B/lane from global (L2-hot)
__device__ __forceinline__ short8 wfrag(const u16* wf, int nt, int kb, int lane) {
    return *(const short8*)(wf + (((kb << 3) + nt) * 64 + lane) * 8);
}
__device__ __forceinline__ void frag_flush(const u16* t, u16* wf, int nt, int lane) {
#pragma unroll
    for (int kb = 0; kb < 4; ++kb)
        *(short8*)(wf + (((kb << 3) + nt) * 64 + lane) * 8) = sfrag(t, 0, kb, lane);
}
__device__ __forceinline__ short8 frag_cvt(const float* base, int r0, int ld, int kb, int lane) {
    const float* p = base + (size_t)(r0 + (lane & 15)) * ld + kb * 32 + (lane >> 4) * 8;
    short8 s;
#pragma unroll
    for (int j = 0; j < 8; ++j) s[j] = (short)f2bf(p[j]);
    return s;
}
__device__ __forceinline__ void tile_store(u16* t, const floatx4* acc, int lane) {
    int col = lane & 15, qd = lane >> 4;
#pragma unroll
    for (int nt = 0; nt < 8; ++nt)
#pragma unroll
        for (int r = 0; r < 4; ++r)
            t[(qd * 4 + r) * LDP + nt * 16 + col] = f2bf(acc[nt][r]);
}
__device__ __forceinline__ void tile_flush(const u16* t, u16* g, int lane) {
#pragma unroll
    for (int it = 0; it < 4; ++it) {
        int chunk = it * 64 + lane, row = chunk >> 4, c8 = chunk & 15;
        *(uint4*)(g + (size_t)row * 128 + c8 * 8) = *(const uint4*)(t + row * LDP + c8 * 8);
    }
}

struct P {
    const int* ei; const float* attr; const float* z0;
    const float* e_w1; const float* e_b1; const float* e_w2; const float* e_b2;
    const float* n_w1; const float* n_b1; const float* ln_g; const float* ln_b;
    const float* n_w2; const float* n_b2;
    int* ofs; int* tgt_s; float* a_s; float* degf;
    u16* wf;        // 6 fragment-major slots: 0=Wc0 1=Wd 2=We 3=Wf 4=Wc1 5=n2_1
    u16* w_n20;     // n2_0 row-major (fin GEMV)
    float* wl; float* vb2;
    float* rx; float* rci; float* rcj; float* rh; float* mx0;
    u16* c0t; u16* S; u16* t1g; u16* ci1; u16* cj1;
    float* out;
};

// ---------------------------------------------------------------------------
// Setup, 20 blocks (latency-parallelized, round-10 version):
// 0 CSR; 1-2 n2_0 cvt; 3 n2_1->frag; 4-13 product GEMMs (direct global B);
// 14 rx; 15-17 rci/rcj/rh; 18 c0; 19 vb2(vectorized)+wl+zero mx0
// ---------------------------------------------------------------------------
__global__ __launch_bounds__(256) void k_setup(P p) {
    __shared__ __align__(16) char smem[17408];
    int tid = threadIdx.x, blk = blockIdx.x;
    int lane = tid & 63, w = tid >> 6, col = lane & 15, qd = lane >> 4;

    if (blk == 0) {                               // CSR build
        __shared__ int cnt[1024];
        __shared__ int wsum[4];
        __shared__ int flag;
#pragma unroll
        for (int i = 0; i < 4; ++i) cnt[tid + i * 256] = 0;
        if (tid == 0) flag = 1;
        __syncthreads();
        if (tid < 100 && p.ei[2 * tid + 1] != 0) atomicAnd(&flag, 0);
        __syncthreads();
        int i64 = flag;
        for (int e = tid; e < E_; e += 256) {
            int s = i64 ? p.ei[2 * e] : p.ei[e];
            atomicAdd(&cnt[s], 1);
        }
        __syncthreads();
        int q0 = tid * 4;
        int c0 = cnt[q0], c1 = cnt[q0 + 1], c2 = cnt[q0 + 2], c3 = cnt[q0 + 3];
        int tsum = c0 + c1 + c2 + c3, incl = tsum;
#pragma unroll
        for (int o = 1; o < 64; o <<= 1) {
            int t = __shfl_up(incl, o, 64);
            if (lane >= o) incl += t;
        }
        if (lane == 63) wsum[w] = incl;
        __syncthreads();
        int wo = 0;
        for (int i = 0; i < w; ++i) wo += wsum[i];
        int base = wo + incl - tsum;
        p.ofs[q0] = base; p.ofs[q0 + 1] = base + c0;
        p.ofs[q0 + 2] = base + c0 + c1; p.ofs[q0 + 3] = base + c0 + c1 + c2;
        p.degf[q0] = (float)c0; p.degf[q0 + 1] = (float)c1;
        p.degf[q0 + 2] = (float)c2; p.degf[q0 + 3] = (float)c3;
        if (tid == 0) p.ofs[NQ_] = E_;
        __syncthreads();
        cnt[q0] = base; cnt[q0 + 1] = base + c0;
        cnt[q0 + 2] = base + c0 + c1; cnt[q0 + 3] = base + c0 + c1 + c2;
        __syncthreads();
        for (int e = tid; e < E_; e += 256) {
            int s = i64 ? p.ei[2 * e]        : p.ei[e];
            int t = i64 ? p.ei[2 * (E_ + e)] : p.ei[E_ + e];
            int pos = atomicAdd(&cnt[s], 1);
            p.tgt_s[pos] = t;
            p.a_s[pos]   = p.attr[e];
        }
    } else if (blk <= 2) {                        // n2_0 row-major cvt, 2 halves
        int base = (blk - 1) * 8192;
        for (int idx = tid; idx < 8192; idx += 256)
            p.w_n20[base + idx] = f2bf(p.n_w2[base + idx]);
    } else if (blk == 3) {                        // n2_1 -> fragment-major slot 5
        const float* src = p.n_w2 + 16384;
        u16* dst = p.wf + 5 * 16384;
        for (int pr = w; pr < 32; pr += 4) {      // pr = kb*8+nt
            int kb = pr >> 3, nt = pr & 7;
            const float* s = src + (nt * 16 + col) * 128 + kb * 32 + qd * 8;
            short8 v;
#pragma unroll
            for (int j = 0; j < 8; ++j) v[j] = (short)f2bf(s[j]);
            *(short8*)(dst + (pr * 64 + lane) * 8) = v;
        }
    } else if (blk <= 13) {                       // product GEMMs, direct B loads
        int g = (blk - 4) >> 1, part = (blk - 4) & 1;
        const float* Pm; const float* Q; int ldp; u16* D;
        switch (g) {
            case 0:  Pm = p.n_w1 + 128;             ldp = 256; Q = p.e_w2;         D = p.wf;             break;
            case 1:  Pm = p.n_w1 + 32768 + 128;     ldp = 256; Q = p.e_w2 + 16384; D = p.wf + 4 * 16384; break;
            case 2:  Pm = p.e_w1 + 128 * 257;       ldp = 257; Q = p.n_w2;         D = p.wf + 1 * 16384; break;
            case 3:  Pm = p.e_w1 + 128 * 257 + 128; ldp = 257; Q = p.n_w2;         D = p.wf + 2 * 16384; break;
            default: Pm = p.n_w1 + 32768;           ldp = 256; Q = p.n_w2;         D = p.wf + 3 * 16384; break;
        }
        int tile = part * 4 + w;                  // 0..7, one 16-row tile per wave
        int r0 = tile * 16;
        floatx4 acc[8] = {};
#pragma unroll
        for (int kb = 0; kb < 4; ++kb) {
            short8 a = frag_cvt(Pm, r0, ldp, kb, lane);
#pragma unroll
            for (int nt = 0; nt < 8; ++nt) {
                short8 bq;                        // B[k][n] = Q[k*128+n], coalesced
#pragma unroll
                for (int j = 0; j < 8; ++j)
                    bq[j] = (short)f2bf(Q[(kb * 32 + qd * 8 + j) * 128 + nt * 16 + col]);
                acc[nt] = mfma16(a, bq, acc[nt]);
            }
        }
        u16* slot = (u16*)smem + w * TILE;
        tile_store(slot, acc, lane); WVB();
        frag_flush(slot, D, tile, lane);
    } else if (blk == 14) {                       // rx = z0@n1a0^T + n_b1_0
        int r0 = w * 16;
        floatx4 acc[8] = {};
#pragma unroll
        for (int kb = 0; kb < 4; ++kb) {
            short8 a = frag_cvt(p.z0, r0, 128, kb, lane);
#pragma unroll
            for (int nt = 0; nt < 8; ++nt)
                acc[nt] = mfma16(a, frag_cvt(p.n_w1, nt * 16, 256, kb, lane), acc[nt]);
        }
#pragma unroll
        for (int nt = 0; nt < 8; ++nt) {
            int cg = nt * 16 + col; float bv = p.n_b1[cg];
#pragma unroll
            for (int r = 0; r < 4; ++r) p.rx[(r0 + qd * 4 + r) * 128 + cg] = acc[nt][r] + bv;
        }
    } else if (blk <= 17) {                       // rci/rcj/rh = (z0+n_b2_0)@W^T (+bias)
        int r0 = w * 16;
        const float* Wp; int ld; const float* bias; float* dst;
        if (blk == 15)      { Wp = p.e_w1 + 128 * 257;       ld = 257; bias = p.e_b1 + 128; dst = p.rci; }
        else if (blk == 16) { Wp = p.e_w1 + 128 * 257 + 128; ld = 257; bias = nullptr;      dst = p.rcj; }
        else                { Wp = p.n_w1 + 32768;           ld = 256; bias = p.n_b1 + 128; dst = p.rh;  }
        floatx4 acc[8] = {};
#pragma unroll
        for (int kb = 0; kb < 4; ++kb) {
            short8 a;
            int rr = (r0 + col) * 128, kk = kb * 32 + qd * 8;
#pragma unroll
            for (int j = 0; j < 8; ++j) a[j] = (short)f2bf(p.z0[rr + kk + j] + p.n_b2[kk + j]);
#pragma unroll
            for (int nt = 0; nt < 8; ++nt)
                acc[nt] = mfma16(a, frag_cvt(Wp, nt * 16, ld, kb, lane), acc[nt]);
        }
#pragma unroll
        for (int nt = 0; nt < 8; ++nt) {
            int cg = nt * 16 + col;
            float bv = bias ? bias[cg] : 0.0f;
#pragma unroll
            for (int r = 0; r < 4; ++r) dst[(r0 + qd * 4 + r) * 128 + cg] = acc[nt][r] + bv;
        }
    } else if (blk == 18) {                       // c0 = z0@(W1a0+W1b0)^T + e_b1_0
        int r0 = w * 16;
        floatx4 a1[8] = {};
#pragma unroll
        for (int kb = 0; kb < 4; ++kb) {
            short8 a = frag_cvt(p.z0, r0, 128, kb, lane);
#pragma unroll
            for (int nt = 0; nt < 8; ++nt) {
                a1[nt] = mfma16(a, frag_cvt(p.e_w1,       nt * 16, 257, kb, lane), a1[nt]);
                a1[nt] = mfma16(a, frag_cvt(p.e_w1 + 128, nt * 16, 257, kb, lane), a1[nt]);
            }
        }
#pragma unroll
        for (int nt = 0; nt < 8; ++nt) {
            float bv = p.e_b1[nt * 16 + col];
#pragma unroll
            for (int r = 0; r < 4; ++r) a1[nt][r] += bv;
        }
        u16* slot = (u16*)smem + w * TILE;
        tile_store(slot, a1, lane); WVB();
        tile_flush(slot, p.c0t + (size_t)r0 * 128, lane);
    } else {                                      // vb2 (vectorized) + wl + zero mx0
        int k = tid >> 7, c = tid & 127;
        const float4* wp = (const float4*)(p.n_w1 + k * 32768 + c * 256 + 128);
        const float4* bp = (const float4*)(p.e_b2 + k * 128);
        float s0 = 0.f, s1 = 0.f, s2 = 0.f, s3 = 0.f;
#pragma unroll
        for (int n4 = 0; n4 < 32; ++n4) {
            float4 a = wp[n4], bv = bp[n4];
            s0 += a.x * bv.x; s1 += a.y * bv.y; s2 += a.z * bv.z; s3 += a.w * bv.w;
        }
        p.vb2[tid] = (s0 + s1) + (s2 + s3);
        p.wl[tid]  = p.e_w1[k * 128 * 257 + c * 257 + 256];
        for (int i = tid; i < 8192; i += 256) p.mx0[i] = 0.0f;
    }
}

// ---------------------------------------------------------------------------
// Edge gather. r0=1: broadcast table c0 (no gather loads). Else full gather.
// wave = one q x 8 batches (shared index stream)
// ---------------------------------------------------------------------------
__global__ __launch_bounds__(256) void k_edge(P p, int r0) {
    int tid = threadIdx.x, lane = tid & 63, w = tid >> 6;
    const float* wl = r0 ? p.wl : p.wl + 128;
    float2 wl2 = ((const float2*)wl)[lane];
    int gw = blockIdx.x * 4 + w;
    int q = gw & (NQ_ - 1), bg = gw >> 10;
    int bl[8];
#pragma unroll
    for (int i = 0; i < 4; ++i) { bl[i] = bg * 4 + i; bl[i + 4] = bg * 4 + i + 32; }
    int st = p.ofs[q], en = p.ofs[q + 1];
    float ax[8] = {}, ay[8] = {};
    if (r0) {
        float cx[8], cy[8];
#pragma unroll
        for (int i = 0; i < 8; ++i) {
            u32 cv = ((const u32*)p.c0t)[(size_t)bl[i] * 64 + lane];
            cx[i] = bf2f((u16)(cv & 0xffff)); cy[i] = bf2f((u16)(cv >> 16));
        }
        for (int idx = st; idx < en; ++idx) {
            float a = p.a_s[idx];
            float wx = a * wl2.x, wy = a * wl2.y;
#pragma unroll
            for (int i = 0; i < 8; ++i) {
                ax[i] += fmaxf(cx[i] + wx, 0.f);
                ay[i] += fmaxf(cy[i] + wy, 0.f);
            }
        }
    } else {
        const u32* cjp[8];
        float cx[8], cy[8];
#pragma unroll
        for (int i = 0; i < 8; ++i) {
            cjp[i] = (const u32*)p.cj1 + (size_t)bl[i] * NQ_ * 64;
            u32 cv = ((const u32*)p.ci1)[((size_t)bl[i] * NQ_ + q) * 64 + lane];
            cx[i] = bf2f((u16)(cv & 0xffff)); cy[i] = bf2f((u16)(cv >> 16));
        }
        for (int idx = st; idx < en; ++idx) {
            int t = p.tgt_s[idx];
            float a = p.a_s[idx];
            size_t ro = (size_t)t * 64 + lane;
            float wx = a * wl2.x, wy = a * wl2.y;
#pragma unroll
            for (int i = 0; i < 8; ++i) {
                u32 jv = cjp[i][ro];
                ax[i] += fmaxf(cx[i] + bf2f((u16)(jv & 0xffff)) + wx, 0.f);
                ay[i] += fmaxf(cy[i] + bf2f((u16)(jv >> 16))    + wy, 0.f);
            }
        }
    }
    u32* Sp = (u32*)p.S;
#pragma unroll
    for (int i = 0; i < 8; ++i)
        Sp[((size_t)bl[i] * NQ_ + q) * 64 + lane] =
            (u32)f2bf(ax[i]) | ((u32)f2bf(ay[i]) << 16);
}

// ---------------------------------------------------------------------------
// node0 (round-8 form): x0 = LN(relu(S@Wc0 + rx + deg*vb2)); mx0 atomics;
//   ci1 = x0@Wd + rci; cj1 = x0@We + rcj; t1 = x0@Wf + rh -> t1g
// No block barriers; weights fragment-major from L2; LDS wave-private.
// ---------------------------------------------------------------------------
__global__ __launch_bounds__(256, 2) void k_node0(P p) {
    __shared__ __align__(16) char smem[52224];
    u16* xt = (u16*)smem;
    u16* ob = (u16*)(smem + 34816);
    int tid = threadIdx.x, lane = tid & 63, w = tid >> 6;
    int col = lane & 15, qd = lane >> 4;
    int blk = blockIdx.x;
    int rowbase = blk * 128 + w * 32;
    int b = blk >> 3;

    floatx4 xa[2][8] = {};
#pragma unroll
    for (int kb = 0; kb < 4; ++kb) {
        short8 Bv[8];
#pragma unroll
        for (int nt = 0; nt < 8; ++nt) Bv[nt] = wfrag(p.wf, nt, kb, lane);
#pragma unroll
        for (int t = 0; t < 2; ++t) {
            short8 a = gfrag(p.S, rowbase + t * 16, kb, lane);
#pragma unroll
            for (int nt = 0; nt < 8; ++nt) xa[t][nt] = mfma16(a, Bv[nt], xa[t][nt]);
        }
    }
    float s8[8] = {};
#pragma unroll
    for (int t = 0; t < 2; ++t) {
#pragma unroll
        for (int nt = 0; nt < 8; ++nt) {
            int cg = nt * 16 + col;
            float base = p.rx[b * 128 + cg], vb = p.vb2[cg];
#pragma unroll
            for (int r = 0; r < 4; ++r) {
                int row = rowbase + t * 16 + qd * 4 + r;
                xa[t][nt][r] = fmaxf(xa[t][nt][r] + base + p.degf[row & (NQ_ - 1)] * vb, 0.f);
            }
        }
#pragma unroll
        for (int r = 0; r < 4; ++r) {
            float s = 0.f, s2 = 0.f;
#pragma unroll
            for (int nt = 0; nt < 8; ++nt) { float v = xa[t][nt][r]; s += v; s2 += v * v; }
#pragma unroll
            for (int o = 1; o < 16; o <<= 1) { s += __shfl_xor(s, o, 64); s2 += __shfl_xor(s2, o, 64); }
            float mu = s * (1.f / 128.f), var = s2 * (1.f / 128.f) - mu * mu;
            float rs = rsqrtf(var + 1e-5f);
#pragma unroll
            for (int nt = 0; nt < 8; ++nt) {
                int cg = nt * 16 + col;
                float xv = (xa[t][nt][r] - mu) * rs * p.ln_g[cg] + p.ln_b[cg];
                xa[t][nt][r] = xv;
                s8[nt] += xv;
            }
        }
        tile_store(xt + (w * 2 + t) * TILE, xa[t], lane);
    }
#pragma unroll
    for (int nt = 0; nt < 8; ++nt) {
        s8[nt] += __shfl_xor(s8[nt], 16, 64);
        s8[nt] += __shfl_xor(s8[nt], 32, 64);
    }
    if (lane < 16) {
#pragma unroll
        for (int nt = 0; nt < 8; ++nt)
            atomicAdd(p.mx0 + b * 128 + nt * 16 + lane, s8[nt]);
    }
    WVB();
#pragma unroll
    for (int ph = 0; ph < 3; ++ph) {
        const u16* wfp = p.wf + ((ph == 0) ? 1 : (ph == 1) ? 2 : 3) * 16384;
        const float* rt = (ph == 0) ? p.rci : (ph == 1) ? p.rcj : p.rh;
        floatx4 ca[2][8] = {};
#pragma unroll
        for (int kb = 0; kb < 4; ++kb) {
            short8 Bv[8];
#pragma unroll
            for (int nt = 0; nt < 8; ++nt) Bv[nt] = wfrag(wfp, nt, kb, lane);
#pragma unroll
            for (int t = 0; t < 2; ++t) {
                short8 a = sfrag(xt + (w * 2 + t) * TILE, 0, kb, lane);
#pragma unroll
                for (int nt = 0; nt < 8; ++nt) ca[t][nt] = mfma16(a, Bv[nt], ca[t][nt]);
            }
        }
#pragma unroll
        for (int t = 0; t < 2; ++t)
#pragma unroll
            for (int nt = 0; nt < 8; ++nt) {
                float rc = rt[b * 128 + nt * 16 + col];
#pragma unroll
                for (int r = 0; r < 4; ++r) ca[t][nt][r] += rc;
            }
        u16* dst = (ph == 0) ? p.ci1 : (ph == 1) ? p.cj1 : p.t1g;
#pragma unroll
        for (int t = 0; t < 2; ++t) {
            tile_store(ob + w * TILE, ca[t], lane);
            WVB();
            tile_flush(ob + w * TILE, dst + (size_t)(rowbase + t * 16) * 128, lane);
            WVB();
        }
    }
}

// ---------------------------------------------------------------------------
// node1: x1 = LN(relu(S@Wc1 + t1 + deg*vb2_1)); out += mean(x1@n2_1); fin
// ---------------------------------------------------------------------------
__global__ __launch_bounds__(256, 2) void k_node1(P p) {
    __shared__ __align__(16) char smem[52224];
    u16* ob = (u16*)(smem + 34816);
    int tid = threadIdx.x, lane = tid & 63, w = tid >> 6;
    int col = lane & 15, qd = lane >> 4;
    int blk = blockIdx.x;
    int rowbase = blk * 128 + w * 32;
    int b = blk >> 3;

    const u16* wc1 = p.wf + 4 * 16384;
    floatx4 xa[2][8] = {};
#pragma unroll
    for (int kb = 0; kb < 4; ++kb) {
        short8 Bv[8];
#pragma unroll
        for (int nt = 0; nt < 8; ++nt) Bv[nt] = wfrag(wc1, nt, kb, lane);
#pragma unroll
        for (int t = 0; t < 2; ++t) {
            short8 a = gfrag(p.S, rowbase + t * 16, kb, lane);
#pragma unroll
            for (int nt = 0; nt < 8; ++nt) xa[t][nt] = mfma16(a, Bv[nt], xa[t][nt]);
        }
    }
    const float* vb21 = p.vb2 + 128;
#pragma unroll
    for (int t = 0; t < 2; ++t) {
#pragma unroll
        for (int nt = 0; nt < 8; ++nt) {
            int cg = nt * 16 + col;
            float vb = vb21[cg];
#pragma unroll
            for (int r = 0; r < 4; ++r) {
                int row = rowbase + t * 16 + qd * 4 + r;
                float tv = bf2f(p.t1g[(size_t)row * 128 + cg]);
                xa[t][nt][r] = fmaxf(xa[t][nt][r] + tv + p.degf[row & (NQ_ - 1)] * vb, 0.f);
            }
        }
#pragma unroll
        for (int r = 0; r < 4; ++r) {
            float s = 0.f, s2 = 0.f;
#pragma unroll
            for (int nt = 0; nt < 8; ++nt) { float v = xa[t][nt][r]; s += v; s2 += v * v; }
#pragma unroll
            for (int o = 1; o < 16; o <<= 1) { s += __shfl_xor(s, o, 64); s2 += __shfl_xor(s2, o, 64); }
            float mu = s * (1.f / 128.f), var = s2 * (1.f / 128.f) - mu * mu;
            float rs = rsqrtf(var + 1e-5f);
#pragma unroll
            for (int nt = 0; nt < 8; ++nt) {
                int cg = nt * 16 + col;
                xa[t][nt][r] = (xa[t][nt][r] - mu) * rs * p.ln_g[128 + cg] + p.ln_b[128 + cg];
            }
        }
    }
    // mean(x1@n2_1): per-wave sequential staging through ob slot
    const u16* n21 = p.wf + 5 * 16384;
    float s8[8] = {};
#pragma unroll
    for (int t = 0; t < 2; ++t) {
        WVB();
        tile_store(ob + w * TILE, xa[t], lane);
        WVB();
        floatx4 ma[8] = {};
#pragma unroll
        for (int kb = 0; kb < 4; ++kb) {
            short8 Bv[8];
#pragma unroll
            for (int nt = 0; nt < 8; ++nt) Bv[nt] = wfrag(n21, nt, kb, lane);
            short8 a = sfrag(ob + w * TILE, 0, kb, lane);
#pragma unroll
            for (int nt = 0; nt < 8; ++nt) ma[nt] = mfma16(a, Bv[nt], ma[nt]);
        }
#pragma unroll
        for (int nt = 0; nt < 8; ++nt)
#pragma unroll
            for (int r = 0; r < 4; ++r) s8[nt] += ma[nt][r];
    }
#pragma unroll
    for (int nt = 0; nt < 8; ++nt) {
        s8[nt] += __shfl_xor(s8[nt], 16, 64);
        s8[nt] += __shfl_xor(s8[nt], 32, 64);
    }
    if (lane < 16) {
#pragma unroll
        for (int nt = 0; nt < 8; ++nt)
            atomicAdd(p.out + b * 128 + nt * 16 + lane, s8[nt] * (1.f / 1024.f));
    }
    // fin: out[b] += z0[b] + n_b2_0 + n_b2_1 + mx0[b]@n2_0^T / 1024  (vectorized)
    if ((blk & 7) == 0 && tid < 128) {
        int c = tid;
        const float* mx = p.mx0 + b * 128;
        float s = 0.f;
#pragma unroll
        for (int k8 = 0; k8 < 16; ++k8) {
            short8 wv = *(const short8*)(p.w_n20 + c * 128 + k8 * 8);
            const float* mxp = mx + k8 * 8;
#pragma unroll
            for (int j = 0; j < 8; ++j) s += mxp[j] * bf2f((u16)wv[j]);
        }
        float acc = p.z0[b * 128 + c] + p.n_b2[c] + p.n_b2[128 + c] + s * (1.f / 1024.f);
        atomicAdd(p.out + b * 128 + c, acc);
    }
}

// ---------------------------------------------------------------------------
extern "C" void kernel_launch(void* const* d_in, const int* in_sizes, int n_in,
                              void* d_out, int out_size, void* d_ws, size_t ws_size,
                              hipStream_t stream) {
    P p;
    p.z0   = (const float*)d_in[0];
    p.ei   = (const int*)d_in[1];
    p.attr = (const float*)d_in[2];
    p.e_w1 = (const float*)d_in[4];
    p.e_b1 = (const float*)d_in[5];
    p.e_w2 = (const float*)d_in[6];
    p.e_b2 = (const float*)d_in[7];
    p.n_w1 = (const float*)d_in[8];
    p.n_b1 = (const float*)d_in[9];
    p.ln_g = (const float*)d_in[10];
    p.ln_b = (const float*)d_in[11];
    p.n_w2 = (const float*)d_in[12];
    p.n_b2 = (const float*)d_in[13];
    p.out  = (float*)d_out;

    const size_t H = (size_t)M_ * L_;
    float* f  = (float*)d_ws;
    p.degf = f;                           // 1024
    p.a_s  = f + 1024;                    // 8192
    p.wl   = p.a_s + 8192;                // 256
    p.vb2  = p.wl + 256;                  // 256
    p.rx   = p.vb2 + 256;                 // 8192
    p.rci  = p.rx + 8192;                 // 8192
    p.rcj  = p.rci + 8192;                // 8192
    p.rh   = p.rcj + 8192;                // 8192
    p.mx0  = p.rh + 8192;                 // 8192
    p.ofs  = (int*)(p.mx0 + 8192);        // 1056
    p.tgt_s = p.ofs + 1056;               // 8192
    p.wf    = (u16*)(p.tgt_s + 8192);     // 6*16384
    p.w_n20 = p.wf + 6 * 16384;           // 16384
    p.c0t   = p.w_n20 + 16384;            // 8192
    p.S     = p.c0t + 8192;               // H
    p.t1g   = p.S + H;                    // H
    p.ci1   = p.t1g + H;                  // H
    p.cj1   = p.ci1 + H;                  // H

    hipMemsetAsync(p.out, 0, 8192 * sizeof(float), stream);

    k_setup<<<20, 256, 0, stream>>>(p);
    k_edge<<<2048, 256, 0, stream>>>(p, 1);
    k_node0<<<512, 256, 0, stream>>>(p);
    k_edge<<<2048, 256, 0, stream>>>(p, 0);
    k_node1<<<512, 256, 0, stream>>>(p);
}